// Round 3
// baseline (463.367 us; speedup 1.0000x reference)
//
#include <hip/hip_runtime.h>
#include <math.h>

#define EPS 1e-8f
#define UMAX 8   // 128-row tiles per block; grid = totalUnits/UMAX = 512

typedef float nfloat4 __attribute__((ext_vector_type(4)));

__device__ __forceinline__ float softplus_f(float x) {
    return (x > 20.0f) ? x : log1pf(expf(x));
}
__device__ __forceinline__ float sigmoid_f(float x) {
    return 1.0f / (1.0f + expf(-x));
}

// Device-scope sense-reversing grid barrier (graph-capture-legal replacement
// for cooperative grid.sync). Producers' stores are released by the
// agent-scope __threadfence (L2 writeback); consumers' acquire fence
// invalidates stale per-XCD L2/L1 lines (G16 discipline). Bounded spin:
// if co-residency were ever violated we produce a wrong answer, not a hang.
__device__ __forceinline__ void grid_barrier(unsigned* cnt, unsigned* gen, unsigned nb) {
    __syncthreads();
    if (threadIdx.x == 0) {
        __threadfence();   // release: all block stores -> device-visible
        unsigned g = __hip_atomic_load(gen, __ATOMIC_RELAXED, __HIP_MEMORY_SCOPE_AGENT);
        unsigned arrived = __hip_atomic_fetch_add(cnt, 1u, __ATOMIC_ACQ_REL, __HIP_MEMORY_SCOPE_AGENT);
        if (arrived == nb - 1u) {
            __hip_atomic_store(cnt, 0u, __ATOMIC_RELAXED, __HIP_MEMORY_SCOPE_AGENT);
            __hip_atomic_fetch_add(gen, 1u, __ATOMIC_RELEASE, __HIP_MEMORY_SCOPE_AGENT);
        } else {
            int tries = 0;
            while (__hip_atomic_load(gen, __ATOMIC_ACQUIRE, __HIP_MEMORY_SCOPE_AGENT) == g) {
                __builtin_amdgcn_s_sleep(2);
                if (++tries > (1 << 24)) break;   // safety valve
            }
        }
        __threadfence();   // acquire: invalidate stale cached copies
    }
    __syncthreads();
}

__global__ void init_barrier(unsigned* bar) {
    __hip_atomic_store(bar + 0, 0u, __ATOMIC_RELAXED, __HIP_MEMORY_SCOPE_AGENT);
    __hip_atomic_store(bar + 1, 0u, __ATOMIC_RELAXED, __HIP_MEMORY_SCOPE_AGENT);
}

// controls per b (792 floats): keys[4][64] | erase[4][64] | write[4][64]
//   | betas[4] | gates[4] | shifts[4][3] | gammas[4]
//
// Single persistent kernel, 2 grid barriers (the two unavoidable global
// reductions: softmax denom S, sharpen normalizer T). Each block owns
// UMAX=8 tiles of 128 rows; e-values / w^gamma persist in LDS across the
// barriers (no evals/wp global round-trips). memory[] is re-read by the
// SAME block in phase 3 -> L3/L2-hot. Boundary e-values for the circular
// 3-tap shift go through a tiny ebnd array (8 floats per tile).
// __launch_bounds__(256,2): <=256 VGPR; ~19.4 KB LDS -> 2 blocks/CU ->
// all 512 blocks co-resident with 2x margin.
__global__ __launch_bounds__(256, 2)
void fused_kernel(const float* __restrict__ memory,
                  const float* __restrict__ controls,
                  const float* __restrict__ prev,
                  float* __restrict__ out,
                  unsigned* __restrict__ bar,
                  float* __restrict__ S_part,
                  float* __restrict__ ebnd,
                  float* __restrict__ T_part,
                  int N, int B, unsigned nblocks)
{
    const int t = threadIdx.x;
    const int ntiles = N >> 7;
    const int totalUnits = B * ntiles;

    __shared__ __align__(16) float e_wp[UMAX][4][128]; // e, then w^gamma
    __shared__ __align__(16) float kk[256];
    __shared__ __align__(16) float scratch[520];       // wi[4][130] | es+pad+wv
    __shared__ float knorm_s[4], betas_s[4];
    __shared__ float scal_gate[4], scal_og[4], scal_s0[4], scal_s1[4], scal_s2[4], scal_gm[4];
    __shared__ float halo_e[8], halo_p[8];
    __shared__ float Ssh[4], invT_s[4];

    // ---------------- Phase 1: e = exp(beta*cos - beta) (bounded (0,1],
    // uniform shift cancels in softmax), tile partials S_part, boundaries.
    for (int u = 0; u < UMAX; u++) {
        int uid = blockIdx.x * UMAX + u;
        if (uid >= totalUnits) break;              // uniform per block
        int b = uid / ntiles, tile = uid - b * ntiles;
        int nbase = tile << 7;
        const float* c = controls + (size_t)b * 792;

        __syncthreads();                           // protect kk reuse
        {
            int h = t >> 6, w = t & 63;
            float kt = tanhf(c[h * 64 + w]);
            kk[h * 64 + w] = kt;
            float nsq = kt * kt;
            #pragma unroll
            for (int m = 1; m < 64; m <<= 1) nsq += __shfl_xor(nsq, m, 64);
            if (w == 0) knorm_s[h] = sqrtf(nsq);
            if (t < 4)  betas_s[t] = softplus_f(c[768 + t]);
        }
        __syncthreads();

        int rq = t >> 4, lane = t & 15;
        float4 k4[4];
        #pragma unroll
        for (int h = 0; h < 4; h++) k4[h] = ((const float4*)(kk + h * 64))[lane];
        float beta_l[4], kn_l[4];
        #pragma unroll
        for (int h = 0; h < 4; h++) { beta_l[h] = betas_s[h]; kn_l[h] = knorm_s[h]; }

        float4 m4[8];
        #pragma unroll
        for (int j = 0; j < 8; j++) {
            int n = nbase + rq + 16 * j;
            m4[j] = ((const float4*)(memory + ((size_t)b * N + n) * 64))[lane];
        }
        #pragma unroll
        for (int j = 0; j < 8; j++) {
            float nsq = m4[j].x * m4[j].x + m4[j].y * m4[j].y
                      + m4[j].z * m4[j].z + m4[j].w * m4[j].w;
            float d[4];
            #pragma unroll
            for (int h = 0; h < 4; h++)
                d[h] = m4[j].x * k4[h].x + m4[j].y * k4[h].y
                     + m4[j].z * k4[h].z + m4[j].w * k4[h].w;
            #pragma unroll
            for (int m = 1; m < 16; m <<= 1) {
                nsq += __shfl_xor(nsq, m, 64);
                #pragma unroll
                for (int h = 0; h < 4; h++) d[h] += __shfl_xor(d[h], m, 64);
            }
            if (lane == 0) {
                float mn = sqrtf(nsq);
                int row = rq + 16 * j;
                #pragma unroll
                for (int h = 0; h < 4; h++) {
                    float s = beta_l[h] * d[h] / (mn * kn_l[h] + EPS);
                    e_wp[u][h][row] = __expf(s - beta_l[h]);
                }
            }
        }
        __syncthreads();
        {
            int h = t >> 6, w = t & 63;
            float v = e_wp[u][h][w] + e_wp[u][h][w + 64];
            #pragma unroll
            for (int m = 1; m < 64; m <<= 1) v += __shfl_xor(v, m, 64);
            if (w == 0) S_part[((size_t)b * 4 + h) * ntiles + tile] = v;
        }
        if (t < 8) {
            int hh = t >> 1, side = t & 1;
            ebnd[(size_t)uid * 8 + hh * 2 + side] = e_wp[u][hh][side ? 127 : 0];
        }
    }

    grid_barrier(bar, bar + 1, nblocks);

    // ---------------- Phase 2: S reduce -> interp -> circular shift ->
    // sharpen (w^gamma overwrites e in LDS) -> tile partials T_part.
    for (int u = 0; u < UMAX; u++) {
        int uid = blockIdx.x * UMAX + u;
        if (uid >= totalUnits) break;
        int b = uid / ntiles, tile = uid - b * ntiles;
        int nbase = tile << 7;
        const float* c = controls + (size_t)b * 792;
        float* wiS = scratch;                      // [4][130], halo at 0/129

        __syncthreads();
        {
            int h = t >> 6, w = t & 63;            // wave h reduces head h
            float v = 0.0f;
            for (int i = w; i < ntiles; i += 64)
                v += S_part[((size_t)b * 4 + h) * ntiles + i];
            #pragma unroll
            for (int m = 1; m < 64; m <<= 1) v += __shfl_xor(v, m, 64);
            if (w == 0) Ssh[h] = v;
        }
        if (t < 4) {
            int h = t;
            float g = sigmoid_f(c[772 + h]);
            scal_gate[h] = g; scal_og[h] = 1.0f - g;
            float r0 = c[776 + h * 3], r1 = c[776 + h * 3 + 1], r2 = c[776 + h * 3 + 2];
            float rmx = fmaxf(r0, fmaxf(r1, r2));
            float e0 = expf(r0 - rmx), e1 = expf(r1 - rmx), e2 = expf(r2 - rmx);
            float si = 1.0f / (e0 + e1 + e2);
            scal_s0[h] = e0 * si; scal_s1[h] = e1 * si; scal_s2[h] = e2 * si;
            scal_gm[h] = 1.0f + softplus_f(c[788 + h]);
        }
        if (t < 8) {                               // circular halo e/prev
            int h = t >> 1, side = t & 1;
            int g = side ? nbase + 128 : nbase - 1;
            if (g < 0) g += N; if (g >= N) g -= N;
            int gt = g >> 7, gr = g & 127;
            halo_e[t] = ebnd[(size_t)(b * ntiles + gt) * 8 + h * 2 + (gr == 127 ? 1 : 0)];
            halo_p[t] = prev[((size_t)b * 4 + h) * N + g];
        }
        __syncthreads();

        int h0 = t >> 7, row = t & 127, h1 = h0 + 2;
        {
            float i0 = 1.0f / Ssh[h0], i1 = 1.0f / Ssh[h1];
            float p0 = prev[((size_t)b * 4 + h0) * N + nbase + row];
            float p1 = prev[((size_t)b * 4 + h1) * N + nbase + row];
            wiS[h0 * 130 + row + 1] = scal_gate[h0] * e_wp[u][h0][row] * i0 + scal_og[h0] * p0;
            wiS[h1 * 130 + row + 1] = scal_gate[h1] * e_wp[u][h1][row] * i1 + scal_og[h1] * p1;
        }
        if (t < 8) {
            int h = t >> 1, side = t & 1;
            wiS[h * 130 + (side ? 129 : 0)] =
                scal_gate[h] * halo_e[t] * (1.0f / Ssh[h]) + scal_og[h] * halo_p[t];
        }
        __syncthreads();
        {
            float ws0 = scal_s0[h0] * wiS[h0 * 130 + row]
                      + scal_s1[h0] * wiS[h0 * 130 + row + 1]
                      + scal_s2[h0] * wiS[h0 * 130 + row + 2];
            float ws1 = scal_s0[h1] * wiS[h1 * 130 + row]
                      + scal_s1[h1] * wiS[h1 * 130 + row + 1]
                      + scal_s2[h1] * wiS[h1 * 130 + row + 2];
            // ws strictly > 0 (softmax>0, prev>=0, gate in (0,1)) -> fast pow
            e_wp[u][h0][row] = __expf(scal_gm[h0] * __logf(ws0));
            e_wp[u][h1][row] = __expf(scal_gm[h1] * __logf(ws1));
        }
        __syncthreads();
        {
            int h = t >> 6, w = t & 63;
            float v = e_wp[u][h][w] + e_wp[u][h][w + 64];
            #pragma unroll
            for (int m = 1; m < 64; m <<= 1) v += __shfl_xor(v, m, 64);
            if (w == 0) T_part[((size_t)b * 4 + h) * ntiles + tile] = v;
        }
    }

    grid_barrier(bar, bar + 1, nblocks);

    // ---------------- Phase 3: T reduce -> out = mem*prod(1-wd*e) + sum wd*w
    // (memory rows re-read by the same block -> L3/L2-hot; nontemporal out)
    for (int u = 0; u < UMAX; u++) {
        int uid = blockIdx.x * UMAX + u;
        if (uid >= totalUnits) break;
        int b = uid / ntiles, tile = uid - b * ntiles;
        int nbase = tile << 7;
        const float* c = controls + (size_t)b * 792;
        float* es_s = scratch;
        float* wv_s = scratch + 260;               // 16B-aligned offset

        __syncthreads();
        {
            int h = t >> 6, w = t & 63;
            float v = 0.0f;
            for (int i = w; i < ntiles; i += 64)
                v += T_part[((size_t)b * 4 + h) * ntiles + i];
            #pragma unroll
            for (int m = 1; m < 64; m <<= 1) v += __shfl_xor(v, m, 64);
            if (w == 0) invT_s[h] = 1.0f / (v + EPS);
        }
        es_s[t] = sigmoid_f(c[256 + t]);
        wv_s[t] = tanhf(c[512 + t]);
        __syncthreads();

        int rq = t >> 4, lane = t & 15;
        float4 e4[4], w4[4];
        #pragma unroll
        for (int h = 0; h < 4; h++) {
            e4[h] = ((const float4*)(es_s + h * 64))[lane];
            w4[h] = ((const float4*)(wv_s + h * 64))[lane];
        }
        float invT_l[4];
        #pragma unroll
        for (int h = 0; h < 4; h++) invT_l[h] = invT_s[h];

        float4 m4[8];
        #pragma unroll
        for (int j = 0; j < 8; j++) {
            int n = nbase + rq + 16 * j;
            m4[j] = ((const float4*)(memory + ((size_t)b * N + n) * 64))[lane];
        }
        #pragma unroll
        for (int j = 0; j < 8; j++) {
            int row = rq + 16 * j;
            int n = nbase + row;
            float4 pe = make_float4(1.f, 1.f, 1.f, 1.f);
            float4 up = make_float4(0.f, 0.f, 0.f, 0.f);
            #pragma unroll
            for (int h = 0; h < 4; h++) {
                float f = e_wp[u][h][row] * invT_l[h];
                pe.x *= 1.0f - f * e4[h].x;  pe.y *= 1.0f - f * e4[h].y;
                pe.z *= 1.0f - f * e4[h].z;  pe.w *= 1.0f - f * e4[h].w;
                up.x += f * w4[h].x;  up.y += f * w4[h].y;
                up.z += f * w4[h].z;  up.w += f * w4[h].w;
            }
            nfloat4 o;
            o.x = m4[j].x * pe.x + up.x;
            o.y = m4[j].y * pe.y + up.y;
            o.z = m4[j].z * pe.z + up.z;
            o.w = m4[j].w * pe.w + up.w;
            nfloat4* op = ((nfloat4*)(out + ((size_t)b * N + n) * 64)) + lane;
            __builtin_nontemporal_store(o, op);
        }
    }
}

// -------------------------------------------------------------------------
extern "C" void kernel_launch(void* const* d_in, const int* in_sizes, int n_in,
                              void* d_out, int out_size, void* d_ws, size_t ws_size,
                              hipStream_t stream) {
    const float* memory   = (const float*)d_in[0];
    const float* controls = (const float*)d_in[1];
    const float* prev     = (const float*)d_in[2];
    float* out = (float*)d_out;

    int B = in_sizes[1] / 792;            // H*(3W+6) = 792
    int N = in_sizes[0] / (B * 64);       // W = 64
    int ntiles = N >> 7;
    int totalUnits = B * ntiles;          // 4096
    unsigned nblocks = (unsigned)((totalUnits + UMAX - 1) / UMAX);  // 512

    // workspace: bar(2 u32, padded to 16 floats) | S_part | T_part | ebnd
    unsigned* bar = (unsigned*)d_ws;
    float* S_part = (float*)d_ws + 16;                     // B*4*ntiles
    float* T_part = S_part + (size_t)B * 4 * ntiles;       // B*4*ntiles
    float* ebnd   = T_part + (size_t)B * 4 * ntiles;       // totalUnits*8

    init_barrier<<<1, 1, 0, stream>>>(bar);
    fused_kernel<<<dim3(nblocks), dim3(256), 0, stream>>>(
        memory, controls, prev, out, bar, S_part, ebnd, T_part, N, B, nblocks);
}